// Round 1
// baseline (5703.725 us; speedup 1.0000x reference)
//
#include <hip/hip_runtime.h>

#define NN 10000
#define NE 320000
#define NG 64
#define D1 128
#define D2 256

constexpr int TS = 64;   // block tile (M and N)
constexpr int KS = 16;   // K tile

// ---------------- GEMM: C[M,N] = A[M,K] @ B (+bias) ----------------
// TRANSB=false: B is [K,N] row-major (B[k*N+n])
// TRANSB=true : B is [N,K] row-major (B[n*K+k])  -- for W^T matmuls
template<bool TRANSB, bool BIAS>
__global__ __launch_bounds__(256)
void gemm_k(const float* __restrict__ A, const float* __restrict__ B,
            const float* __restrict__ bias, float* __restrict__ C,
            int M, int N, int K) {
    __shared__ float As[KS][TS + 4];
    __shared__ float Bs[KS][TS + 4];
    const int tid = threadIdx.x;          // 256 threads
    const int tx = tid & 15, ty = tid >> 4;
    const int bm = blockIdx.y * TS, bn = blockIdx.x * TS;
    float acc[4][4] = {};
    for (int k0 = 0; k0 < K; k0 += KS) {
        // A tile: 64 rows x 16 k, transposed into As[k][row]
#pragma unroll
        for (int p = 0; p < 4; ++p) {
            int r = p * 16 + ty;
            int gr = bm + r;
            As[tx][r] = (gr < M) ? A[gr * K + k0 + tx] : 0.f;
        }
        if (TRANSB) {
            // Bs[k][c] = B[(bn+c)*K + k0+k] ; N is a multiple of 64 -> no guard
#pragma unroll
            for (int p = 0; p < 4; ++p) {
                int c = p * 16 + ty;
                Bs[tx][c] = B[(bn + c) * K + k0 + tx];
            }
        } else {
#pragma unroll
            for (int p = 0; p < 4; ++p) {
                int kk = p * 4 + (tid >> 6);
                Bs[kk][tid & 63] = B[(k0 + kk) * N + bn + (tid & 63)];
            }
        }
        __syncthreads();
#pragma unroll
        for (int k = 0; k < KS; ++k) {
            float4 a4 = *(const float4*)&As[k][ty * 4];
            float4 b4 = *(const float4*)&Bs[k][tx * 4];
            float ar[4] = {a4.x, a4.y, a4.z, a4.w};
            float br[4] = {b4.x, b4.y, b4.z, b4.w};
#pragma unroll
            for (int i = 0; i < 4; ++i)
#pragma unroll
                for (int j = 0; j < 4; ++j)
                    acc[i][j] = fmaf(ar[i], br[j], acc[i][j]);
        }
        __syncthreads();
    }
#pragma unroll
    for (int i = 0; i < 4; ++i) {
        int gr = bm + ty * 4 + i;
        if (gr >= M) continue;
#pragma unroll
        for (int j = 0; j < 4; ++j) {
            int gc = bn + tx * 4 + j;
            float v = acc[i][j];
            if (BIAS) v += bias[gc];
            C[gr * N + gc] = v;
        }
    }
}

// ------------- edge scatter: a[dst[e], :] += m[src[e], :] -------------
// one thread = 4 channels of one edge
__global__ void scatter_k(const float* __restrict__ m, const int* __restrict__ src,
                          const int* __restrict__ dst, float* __restrict__ a,
                          int C, int total) {
    int t = blockIdx.x * blockDim.x + threadIdx.x;
    if (t >= total) return;
    int c4 = C >> 2;
    int e = t / c4;
    int c = (t - e * c4) * 4;
    int s = src[e], d = dst[e];
    float4 v = *(const float4*)(m + s * C + c);
    float* ap = a + d * C + c;
    atomicAdd(ap + 0, v.x);
    atomicAdd(ap + 1, v.y);
    atomicAdd(ap + 2, v.z);
    atomicAdd(ap + 3, v.w);
}

// ------------- GRU gates: x = (1-z)*n + z*h (in place on x) -------------
__global__ void gates_k(const float* __restrict__ gi, const float* __restrict__ gh,
                        float* __restrict__ x, int C, int total) {
    int t = blockIdx.x * blockDim.x + threadIdx.x;
    if (t >= total) return;
    int n = t / C, c = t - n * C;
    const float* gin = gi + n * 3 * C;
    const float* ghn = gh + n * 3 * C;
    float ir = gin[c], iz = gin[C + c], in_ = gin[2 * C + c];
    float hr = ghn[c], hz = ghn[C + c], hn = ghn[2 * C + c];
    float h = x[t];
    float r = 1.f / (1.f + expf(-(ir + hr)));
    float z = 1.f / (1.f + expf(-(iz + hz)));
    float nn = tanhf(in_ + r * hn);
    x[t] = (1.f - z) * nn + z * h;
}

// ------------- relu + pad 128 -> 256 -------------
__global__ void relu_pad_k(const float* __restrict__ x1, float* __restrict__ x2, int total) {
    int t = blockIdx.x * blockDim.x + threadIdx.x;
    if (t >= total) return;
    int n = t >> 8, c = t & 255;
    x2[t] = (c < D1) ? fmaxf(x1[n * D1 + c], 0.f) : 0.f;
}

// ------------- segment max pool (monotone uint mapping) -------------
__global__ void pool_init_k(unsigned* __restrict__ pool) {
    int t = blockIdx.x * blockDim.x + threadIdx.x;
    if (t < NG * D2) pool[t] = 0x007FFFFFu;  // mapped(-inf)
}

__global__ void pool_max_k(const float* __restrict__ x, const int* __restrict__ batch,
                           unsigned* __restrict__ pool, int total) {
    int t = blockIdx.x * blockDim.x + threadIdx.x;
    if (t >= total) return;
    int n = t >> 8, c = t & 255;
    unsigned b = __float_as_uint(x[t]);
    unsigned u = (b & 0x80000000u) ? ~b : (b | 0x80000000u);
    atomicMax(&pool[batch[n] * D2 + c], u);
}

// ------------- final FC: out[g,o] = pool[g,:] . fc_w[o,:] + fc_b[o] -------------
__global__ void fc_k(const unsigned* __restrict__ pool, const float* __restrict__ w,
                     const float* __restrict__ b, float* __restrict__ out) {
    int t = blockIdx.x * blockDim.x + threadIdx.x;
    if (t >= NG * 6) return;
    int g = t / 6, o = t - g * 6;
    float s = b[o];
    for (int c = 0; c < D2; ++c) {
        unsigned u = pool[g * D2 + c];
        unsigned bits = (u & 0x80000000u) ? (u ^ 0x80000000u) : ~u;
        s += __uint_as_float(bits) * w[o * D2 + c];
    }
    out[t] = s;
}

// =======================================================================
extern "C" void kernel_launch(void* const* d_in, const int* in_sizes, int n_in,
                              void* d_out, int out_size, void* d_ws, size_t ws_size,
                              hipStream_t stream) {
    const float* x_in = (const float*)d_in[0];
    const int* ei = (const int*)d_in[1];
    const int* src = ei;
    const int* dst = ei + NE;
    const int* batch = (const int*)d_in[2];
    const float* w1   = (const float*)d_in[3];
    const float* wih1 = (const float*)d_in[4];
    const float* whh1 = (const float*)d_in[5];
    const float* bih1 = (const float*)d_in[6];
    const float* bhh1 = (const float*)d_in[7];
    const float* w2   = (const float*)d_in[8];
    const float* wih2 = (const float*)d_in[9];
    const float* whh2 = (const float*)d_in[10];
    const float* bih2 = (const float*)d_in[11];
    const float* bhh2 = (const float*)d_in[12];
    const float* fcw  = (const float*)d_in[13];
    const float* fcb  = (const float*)d_in[14];
    float* out = (float*)d_out;

    // workspace layout (floats)
    float* ws   = (float*)d_ws;
    float* xbuf = ws;                  // [NN, 256] (layer1 uses [NN,128] compact)
    float* mbuf = xbuf + NN * D2;      // [NN, 256]
    float* abuf = mbuf + NN * D2;      // [NN, 256]
    float* gibuf = abuf + NN * D2;     // [NN, 768]
    float* ghbuf = gibuf + NN * 3 * D2;// [NN, 768]
    unsigned* pool = (unsigned*)(ghbuf + NN * 3 * D2);  // [NG, 256]

    const int MT = (NN + TS - 1) / TS;  // 157 row tiles

    // x1 = x (copy, we mutate it)
    hipMemcpyAsync(xbuf, x_in, (size_t)NN * D1 * sizeof(float),
                   hipMemcpyDeviceToDevice, stream);

    // ---------------- layer 1 (C = 128, 3 iters) ----------------
    for (int it = 0; it < 3; ++it) {
        const int C = D1;
        gemm_k<false, false><<<dim3(C / TS, MT), 256, 0, stream>>>(
            xbuf, w1 + it * C * C, nullptr, mbuf, NN, C, C);
        hipMemsetAsync(abuf, 0, (size_t)NN * C * sizeof(float), stream);
        {
            int total = NE * (C / 4);
            scatter_k<<<(total + 255) / 256, 256, 0, stream>>>(mbuf, src, dst, abuf, C, total);
        }
        gemm_k<true, true><<<dim3(3 * C / TS, MT), 256, 0, stream>>>(
            abuf, wih1, bih1, gibuf, NN, 3 * C, C);
        gemm_k<true, true><<<dim3(3 * C / TS, MT), 256, 0, stream>>>(
            xbuf, whh1, bhh1, ghbuf, NN, 3 * C, C);
        {
            int total = NN * C;
            gates_k<<<(total + 255) / 256, 256, 0, stream>>>(gibuf, ghbuf, xbuf, C, total);
        }
    }

    // relu + pad to 256 (stage via gibuf to avoid in-place overlap)
    {
        int total = NN * D2;
        relu_pad_k<<<(total + 255) / 256, 256, 0, stream>>>(xbuf, gibuf, total);
        hipMemcpyAsync(xbuf, gibuf, (size_t)total * sizeof(float),
                       hipMemcpyDeviceToDevice, stream);
    }

    // ---------------- layer 2 (C = 256, 3 iters) ----------------
    for (int it = 0; it < 3; ++it) {
        const int C = D2;
        gemm_k<false, false><<<dim3(C / TS, MT), 256, 0, stream>>>(
            xbuf, w2 + it * C * C, nullptr, mbuf, NN, C, C);
        hipMemsetAsync(abuf, 0, (size_t)NN * C * sizeof(float), stream);
        {
            int total = NE * (C / 4);
            scatter_k<<<(total + 255) / 256, 256, 0, stream>>>(mbuf, src, dst, abuf, C, total);
        }
        gemm_k<true, true><<<dim3(3 * C / TS, MT), 256, 0, stream>>>(
            abuf, wih2, bih2, gibuf, NN, 3 * C, C);
        gemm_k<true, true><<<dim3(3 * C / TS, MT), 256, 0, stream>>>(
            xbuf, whh2, bhh2, ghbuf, NN, 3 * C, C);
        {
            int total = NN * C;
            gates_k<<<(total + 255) / 256, 256, 0, stream>>>(gibuf, ghbuf, xbuf, C, total);
        }
    }

    // ---------------- global max pool + FC ----------------
    pool_init_k<<<(NG * D2 + 255) / 256, 256, 0, stream>>>(pool);
    {
        int total = NN * D2;
        pool_max_k<<<(total + 255) / 256, 256, 0, stream>>>(xbuf, batch, pool, total);
    }
    fc_k<<<1, 512, 0, stream>>>(pool, fcw, fcb, out);
}

// Round 2
// 977.317 us; speedup vs baseline: 5.8361x; 5.8361x over previous
//
#include <hip/hip_runtime.h>

#define NN 10000
#define NE 320000
#define NG 64
#define D1 128
#define D2 256

// =====================================================================
// GEMM 64x64 tile, 4x4 microtile (for narrow-N m-GEMMs)
// C[M,N] = A[M,K] @ B (+bias). TRANSB: B is [N,K] row-major.
// blockIdx.z selects operand set 0/1 (for fused dual-GEMM launches).
// =====================================================================
constexpr int KS = 16;

template<bool TRANSB, bool BIAS>
__global__ __launch_bounds__(256)
void gemm64_k(const float* __restrict__ A0, const float* __restrict__ B0,
              const float* __restrict__ bias0, float* __restrict__ C0,
              const float* __restrict__ A1, const float* __restrict__ B1,
              const float* __restrict__ bias1, float* __restrict__ C1,
              int M, int N, int K) {
    const float* A = blockIdx.z ? A1 : A0;
    const float* B = blockIdx.z ? B1 : B0;
    const float* bias = blockIdx.z ? bias1 : bias0;
    float* C = blockIdx.z ? C1 : C0;
    __shared__ float As[KS][64 + 4];
    __shared__ float Bs[KS][64 + 4];
    const int tid = threadIdx.x;
    const int tx = tid & 15, ty = tid >> 4;
    const int bm = blockIdx.y * 64, bn = blockIdx.x * 64;
    float acc[4][4] = {};
    for (int k0 = 0; k0 < K; k0 += KS) {
#pragma unroll
        for (int p = 0; p < 4; ++p) {
            int r = p * 16 + ty;
            int gr = bm + r;
            As[tx][r] = (gr < M) ? A[(size_t)gr * K + k0 + tx] : 0.f;
        }
        if (TRANSB) {
#pragma unroll
            for (int p = 0; p < 4; ++p) {
                int c = p * 16 + ty;
                Bs[tx][c] = B[(size_t)(bn + c) * K + k0 + tx];
            }
        } else {
#pragma unroll
            for (int p = 0; p < 4; ++p) {
                int kk = p * 4 + (tid >> 6);
                Bs[kk][tid & 63] = B[(size_t)(k0 + kk) * N + bn + (tid & 63)];
            }
        }
        __syncthreads();
#pragma unroll
        for (int k = 0; k < KS; ++k) {
            float4 a4 = *(const float4*)&As[k][ty * 4];
            float4 b4 = *(const float4*)&Bs[k][tx * 4];
            float ar[4] = {a4.x, a4.y, a4.z, a4.w};
            float br[4] = {b4.x, b4.y, b4.z, b4.w};
#pragma unroll
            for (int i = 0; i < 4; ++i)
#pragma unroll
                for (int j = 0; j < 4; ++j)
                    acc[i][j] = fmaf(ar[i], br[j], acc[i][j]);
        }
        __syncthreads();
    }
#pragma unroll
    for (int i = 0; i < 4; ++i) {
        int gr = bm + ty * 4 + i;
        if (gr >= M) continue;
#pragma unroll
        for (int j = 0; j < 4; ++j) {
            int gc = bn + tx * 4 + j;
            float v = acc[i][j];
            if (BIAS) v += bias[gc];
            C[(size_t)gr * N + gc] = v;
        }
    }
}

// =====================================================================
// GEMM 128x128 tile, 8x8 microtile split 2x2 (for wide gate GEMMs)
// =====================================================================
template<bool TRANSB, bool BIAS>
__global__ __launch_bounds__(256)
void gemm128_k(const float* __restrict__ A0, const float* __restrict__ B0,
               const float* __restrict__ bias0, float* __restrict__ C0,
               const float* __restrict__ A1, const float* __restrict__ B1,
               const float* __restrict__ bias1, float* __restrict__ C1,
               int M, int N, int K) {
    const float* A = blockIdx.z ? A1 : A0;
    const float* B = blockIdx.z ? B1 : B0;
    const float* bias = blockIdx.z ? bias1 : bias0;
    float* C = blockIdx.z ? C1 : C0;
    constexpr int TK = 16;
    __shared__ float As[TK][132];
    __shared__ float Bs[TK][132];
    const int tid = threadIdx.x;
    const int tn = tid & 15, tm = tid >> 4;
    const int bm = blockIdx.y * 128, bn = blockIdx.x * 128;
    float acc[2][2][4][4] = {};
    for (int k0 = 0; k0 < K; k0 += TK) {
        // A tile: 128 rows x 16 k -> As[k][row]
#pragma unroll
        for (int it = 0; it < 2; ++it) {
            int idx = it * 256 + tid;
            int row = idx >> 2, kq = (idx & 3) * 4;
            int gr = bm + row;
            float4 v = make_float4(0.f, 0.f, 0.f, 0.f);
            if (gr < M) v = *(const float4*)(A + (size_t)gr * K + k0 + kq);
            As[kq + 0][row] = v.x; As[kq + 1][row] = v.y;
            As[kq + 2][row] = v.z; As[kq + 3][row] = v.w;
        }
        if (TRANSB) {
#pragma unroll
            for (int it = 0; it < 2; ++it) {
                int idx = it * 256 + tid;
                int col = idx >> 2, kq = (idx & 3) * 4;
                float4 v = *(const float4*)(B + (size_t)(bn + col) * K + k0 + kq);
                Bs[kq + 0][col] = v.x; Bs[kq + 1][col] = v.y;
                Bs[kq + 2][col] = v.z; Bs[kq + 3][col] = v.w;
            }
        } else {
#pragma unroll
            for (int it = 0; it < 2; ++it) {
                int idx = it * 256 + tid;
                int kk = idx >> 5, nq = (idx & 31) * 4;
                float4 v = *(const float4*)(B + (size_t)(k0 + kk) * N + bn + nq);
                *(float4*)&Bs[kk][nq] = v;
            }
        }
        __syncthreads();
#pragma unroll
        for (int k = 0; k < TK; ++k) {
            float4 a0 = *(const float4*)&As[k][tm * 4];
            float4 a1 = *(const float4*)&As[k][64 + tm * 4];
            float4 b0 = *(const float4*)&Bs[k][tn * 4];
            float4 b1 = *(const float4*)&Bs[k][64 + tn * 4];
            float av[2][4] = {{a0.x, a0.y, a0.z, a0.w}, {a1.x, a1.y, a1.z, a1.w}};
            float bv[2][4] = {{b0.x, b0.y, b0.z, b0.w}, {b1.x, b1.y, b1.z, b1.w}};
#pragma unroll
            for (int hm = 0; hm < 2; ++hm)
#pragma unroll
                for (int i = 0; i < 4; ++i)
#pragma unroll
                    for (int hn = 0; hn < 2; ++hn)
#pragma unroll
                        for (int j = 0; j < 4; ++j)
                            acc[hm][hn][i][j] = fmaf(av[hm][i], bv[hn][j], acc[hm][hn][i][j]);
        }
        __syncthreads();
    }
#pragma unroll
    for (int hm = 0; hm < 2; ++hm)
#pragma unroll
        for (int i = 0; i < 4; ++i) {
            int gr = bm + hm * 64 + tm * 4 + i;
            if (gr >= M) continue;
#pragma unroll
            for (int hn = 0; hn < 2; ++hn) {
                int gc = bn + hn * 64 + tn * 4;
                float4 o = make_float4(acc[hm][hn][i][0], acc[hm][hn][i][1],
                                       acc[hm][hn][i][2], acc[hm][hn][i][3]);
                if (BIAS) {
                    o.x += bias[gc + 0]; o.y += bias[gc + 1];
                    o.z += bias[gc + 2]; o.w += bias[gc + 3];
                }
                *(float4*)(C + (size_t)gr * N + gc) = o;
            }
        }
}

// =====================================================================
// CSR build: count -> scan -> fill
// =====================================================================
__global__ void count_k(const int* __restrict__ dst, int* __restrict__ cnt) {
    int e = blockIdx.x * blockDim.x + threadIdx.x;
    if (e < NE) atomicAdd(&cnt[dst[e]], 1);
}

__global__ void scan_k(const int* __restrict__ cnt, int* __restrict__ off,
                       int* __restrict__ cur) {
    __shared__ int ps[1024];
    const int tid = threadIdx.x;
    const int CH = (NN + 1023) / 1024;  // 10
    const int base = tid * CH;
    int s = 0;
    for (int i = 0; i < CH; ++i) {
        int idx = base + i;
        if (idx < NN) s += cnt[idx];
    }
    ps[tid] = s;
    __syncthreads();
    for (int d = 1; d < 1024; d <<= 1) {
        int v = (tid >= d) ? ps[tid - d] : 0;
        __syncthreads();
        ps[tid] += v;
        __syncthreads();
    }
    int run = (tid > 0) ? ps[tid - 1] : 0;
    for (int i = 0; i < CH; ++i) {
        int idx = base + i;
        if (idx <= NN) { off[idx] = run; if (idx < NN) cur[idx] = run; }
        if (idx < NN) run += cnt[idx];
    }
}

__global__ void fill_k(const int* __restrict__ src, const int* __restrict__ dst,
                       int* __restrict__ cur, int* __restrict__ elist) {
    int e = blockIdx.x * blockDim.x + threadIdx.x;
    if (e >= NE) return;
    int p = atomicAdd(&cur[dst[e]], 1);
    elist[p] = src[e];
}

// =====================================================================
// CSR gather: a[n,:] = sum over incoming edges of m[src,:]
// one group of C/4 lanes per node, float4 per lane
// =====================================================================
template<int C>
__global__ void gather_k(const float* __restrict__ m, const int* __restrict__ off,
                         const int* __restrict__ elist, float* __restrict__ a) {
    constexpr int LPN = C / 4;
    int t = blockIdx.x * blockDim.x + threadIdx.x;
    int node = t / LPN;
    if (node >= NN) return;
    int c = (t % LPN) * 4;
    int s0 = off[node], s1 = off[node + 1];
    float4 acc = make_float4(0.f, 0.f, 0.f, 0.f);
    for (int i = s0; i < s1; ++i) {
        int s = elist[i];
        float4 v = *(const float4*)(m + (size_t)s * C + c);
        acc.x += v.x; acc.y += v.y; acc.z += v.z; acc.w += v.w;
    }
    *(float4*)(a + (size_t)node * C + c) = acc;
}

// =====================================================================
// GRU gates: x = (1-z)*n + z*h, float4
// =====================================================================
template<int C>
__global__ void gates_k(const float* __restrict__ gi, const float* __restrict__ gh,
                        float* __restrict__ x) {
    constexpr int Q = C / 4;
    int t = blockIdx.x * blockDim.x + threadIdx.x;
    if (t >= NN * Q) return;
    int n = t / Q, q = t % Q;
    const float4* gin = (const float4*)(gi + (size_t)n * 3 * C);
    const float4* ghn = (const float4*)(gh + (size_t)n * 3 * C);
    float4 ir = gin[q], iz = gin[Q + q], in_ = gin[2 * Q + q];
    float4 hr = ghn[q], hz = ghn[Q + q], hn = ghn[2 * Q + q];
    float4* xp = (float4*)(x + (size_t)n * C);
    float4 h = xp[q];
    float4 o;
#define GRU1(f)                                                        \
    {                                                                  \
        float r = 1.f / (1.f + expf(-(ir.f + hr.f)));                  \
        float z = 1.f / (1.f + expf(-(iz.f + hz.f)));                  \
        float nn_ = tanhf(in_.f + r * hn.f);                           \
        o.f = (1.f - z) * nn_ + z * h.f;                               \
    }
    GRU1(x) GRU1(y) GRU1(z) GRU1(w)
#undef GRU1
    xp[q] = o;
}

// ------------- relu + pad 128 -> 256 (float4) -------------
__global__ void relu_pad_k(const float* __restrict__ x1, float* __restrict__ x2) {
    int t = blockIdx.x * blockDim.x + threadIdx.x;
    if (t >= NN * 64) return;
    int n = t >> 6, q = t & 63;
    float4 v = make_float4(0.f, 0.f, 0.f, 0.f);
    if (q < 32) {
        float4 u = ((const float4*)(x1 + (size_t)n * 128))[q];
        v.x = fmaxf(u.x, 0.f); v.y = fmaxf(u.y, 0.f);
        v.z = fmaxf(u.z, 0.f); v.w = fmaxf(u.w, 0.f);
    }
    ((float4*)(x2 + (size_t)n * 256))[q] = v;
}

// ------------- segment max pool (monotone uint mapping) -------------
__global__ void pool_init_k(unsigned* __restrict__ pool) {
    int t = blockIdx.x * blockDim.x + threadIdx.x;
    if (t < NG * D2) pool[t] = 0x007FFFFFu;  // mapped(-inf)
}

__global__ void pool_max_k(const float* __restrict__ x, const int* __restrict__ batch,
                           unsigned* __restrict__ pool, int total) {
    int t = blockIdx.x * blockDim.x + threadIdx.x;
    if (t >= total) return;
    int n = t >> 8, c = t & 255;
    unsigned b = __float_as_uint(x[t]);
    unsigned u = (b & 0x80000000u) ? ~b : (b | 0x80000000u);
    atomicMax(&pool[batch[n] * D2 + c], u);
}

__global__ void fc_k(const unsigned* __restrict__ pool, const float* __restrict__ w,
                     const float* __restrict__ b, float* __restrict__ out) {
    int t = blockIdx.x * blockDim.x + threadIdx.x;
    if (t >= NG * 6) return;
    int g = t / 6, o = t - g * 6;
    float s = b[o];
    for (int c = 0; c < D2; ++c) {
        unsigned u = pool[g * D2 + c];
        unsigned bits = (u & 0x80000000u) ? (u ^ 0x80000000u) : ~u;
        s += __uint_as_float(bits) * w[o * D2 + c];
    }
    out[t] = s;
}

// =======================================================================
extern "C" void kernel_launch(void* const* d_in, const int* in_sizes, int n_in,
                              void* d_out, int out_size, void* d_ws, size_t ws_size,
                              hipStream_t stream) {
    const float* x_in = (const float*)d_in[0];
    const int* ei = (const int*)d_in[1];
    const int* src = ei;
    const int* dst = ei + NE;
    const int* batch = (const int*)d_in[2];
    const float* w1   = (const float*)d_in[3];
    const float* wih1 = (const float*)d_in[4];
    const float* whh1 = (const float*)d_in[5];
    const float* bih1 = (const float*)d_in[6];
    const float* bhh1 = (const float*)d_in[7];
    const float* w2   = (const float*)d_in[8];
    const float* wih2 = (const float*)d_in[9];
    const float* whh2 = (const float*)d_in[10];
    const float* bih2 = (const float*)d_in[11];
    const float* bhh2 = (const float*)d_in[12];
    const float* fcw  = (const float*)d_in[13];
    const float* fcb  = (const float*)d_in[14];
    float* out = (float*)d_out;

    // workspace layout (floats). xbuf1 aliases the upper (unused in layer 1)
    // half of gibuf: layer-1 gi uses only [0, NN*384); xbuf1 dies before
    // layer 2 writes the full gibuf.
    float* ws    = (float*)d_ws;
    float* xbuf2 = ws;                  // [NN, 256]
    float* mbuf  = xbuf2 + NN * 256;    // [NN, 256] (layer1 compact [NN,128])
    float* abuf  = mbuf + NN * 256;     // [NN, 256] (layer1 compact [NN,128])
    float* gibuf = abuf + NN * 256;     // [NN, 768]
    float* ghbuf = gibuf + NN * 768;    // [NN, 768]
    float* xbuf1 = gibuf + NN * 384;    // [NN, 128] alias
    unsigned* pool = (unsigned*)(ghbuf + NN * 768);     // [NG, 256]
    int* cnt   = (int*)(pool + NG * D2);                // [NN]
    int* off   = cnt + NN;                              // [NN+1]
    int* cur   = off + NN + 1;                          // [NN]
    int* elist = cur + NN;                              // [NE]

    // ---- CSR build (same edges every iteration) ----
    hipMemsetAsync(cnt, 0, NN * sizeof(int), stream);
    count_k<<<(NE + 255) / 256, 256, 0, stream>>>(dst, cnt);
    scan_k<<<1, 1024, 0, stream>>>(cnt, off, cur);
    fill_k<<<(NE + 255) / 256, 256, 0, stream>>>(src, dst, cur, elist);

    // x1 = x (copy; we mutate it)
    hipMemcpyAsync(xbuf1, x_in, (size_t)NN * D1 * sizeof(float),
                   hipMemcpyDeviceToDevice, stream);

    const int MT64 = (NN + 63) / 64;    // 157
    const int MT128 = (NN + 127) / 128; // 79

    // ---------------- layer 1 (C = 128, 3 iters) ----------------
    for (int it = 0; it < 3; ++it) {
        const int C = D1;
        gemm64_k<false, false><<<dim3(C / 64, MT64, 1), 256, 0, stream>>>(
            xbuf1, w1 + it * C * C, nullptr, mbuf,
            xbuf1, w1 + it * C * C, nullptr, mbuf, NN, C, C);
        gather_k<D1><<<(NN * (D1 / 4) + 255) / 256, 256, 0, stream>>>(
            mbuf, off, elist, abuf);
        gemm128_k<true, true><<<dim3(3 * C / 128, MT128, 2), 256, 0, stream>>>(
            abuf, wih1, bih1, gibuf,
            xbuf1, whh1, bhh1, ghbuf, NN, 3 * C, C);
        gates_k<D1><<<(NN * (D1 / 4) + 255) / 256, 256, 0, stream>>>(
            gibuf, ghbuf, xbuf1);
    }

    // relu + pad to 256
    relu_pad_k<<<(NN * 64 + 255) / 256, 256, 0, stream>>>(xbuf1, xbuf2);

    // ---------------- layer 2 (C = 256, 3 iters) ----------------
    for (int it = 0; it < 3; ++it) {
        const int C = D2;
        gemm64_k<false, false><<<dim3(C / 64, MT64, 1), 256, 0, stream>>>(
            xbuf2, w2 + it * C * C, nullptr, mbuf,
            xbuf2, w2 + it * C * C, nullptr, mbuf, NN, C, C);
        gather_k<D2><<<(NN * (D2 / 4) + 255) / 256, 256, 0, stream>>>(
            mbuf, off, elist, abuf);
        gemm128_k<true, true><<<dim3(3 * C / 128, MT128, 2), 256, 0, stream>>>(
            abuf, wih2, bih2, gibuf,
            xbuf2, whh2, bhh2, ghbuf, NN, 3 * C, C);
        gates_k<D2><<<(NN * (D2 / 4) + 255) / 256, 256, 0, stream>>>(
            gibuf, ghbuf, xbuf2);
    }

    // ---------------- global max pool + FC ----------------
    pool_init_k<<<(NG * D2 + 255) / 256, 256, 0, stream>>>(pool);
    pool_max_k<<<(NN * D2 + 255) / 256, 256, 0, stream>>>(xbuf2, batch, pool, NN * D2);
    fc_k<<<1, 512, 0, stream>>>(pool, fcw, fcb, out);
}

// Round 3
// 830.137 us; speedup vs baseline: 6.8708x; 1.1773x over previous
//
#include <hip/hip_runtime.h>

#define NN 10000
#define NE 320000
#define NG 64
#define D1 128
#define D2 256

typedef unsigned short u16;
typedef short v8s __attribute__((ext_vector_type(8)));
typedef float v4f __attribute__((ext_vector_type(4)));

__device__ __forceinline__ u16 f2bf(float x) {
    unsigned u = __float_as_uint(x);
    return (u16)((u + 0x7fffu + ((u >> 16) & 1u)) >> 16);
}
__device__ __forceinline__ float bf2f(u16 b) {
    return __uint_as_float(((unsigned)b) << 16);
}

// async global->LDS, 16B per lane; LDS dest = wave-uniform base + lane*16
#define GLDS16(gp, lp)                                                         \
    __builtin_amdgcn_global_load_lds(                                          \
        (__attribute__((address_space(1))) unsigned int*)(unsigned long long)(gp), \
        (__attribute__((address_space(3))) unsigned int*)(lp), 16, 0, 0)

// =====================================================================
// Split-bf16 MFMA GEMM: C[M,N] = (Ah+Al)[M,K] @ (Bh+Bl)[N,K]^T (+bias)
// A,B bf16 row-major with row stride K. 128x128 block tile, 4 waves,
// 64x64 per wave, 16x16x32 mfma, BK=32, 3 mfma per frag pair (drop lo*lo).
// A rows >= M read slack memory (harmless: those D rows are never stored).
// =====================================================================
template<bool BIAS>
__global__ __launch_bounds__(256)
void mgemm_k(const u16* __restrict__ Ah, const u16* __restrict__ Al,
             const u16* __restrict__ Bh, const u16* __restrict__ Bl,
             const float* __restrict__ bias, float* __restrict__ C,
             int M, int N, int K) {
    // LDS: 4 regions (Ah, Al, Bh, Bl), each 512 slots x 8 u16 (16B) = 8KB
    // slot sigma = kh*128 + row ; fragment reads are lane-consecutive 16B
    __shared__ u16 lds[16384];
    const int tid = threadIdx.x;
    const int wave = tid >> 6, lane = tid & 63;
    const int wm = (wave >> 1) * 64, wn = (wave & 1) * 64;
    const int bm = blockIdx.y * 128, bn = blockIdx.x * 128;
    const int quad = lane >> 4, r16 = lane & 15;

    v4f acc[4][4] = {};

    for (int k0 = 0; k0 < K; k0 += 32) {
        // stage: wave w covers kh=w for all 128 rows (2 instrs of 64 rows)
#pragma unroll
        for (int j = 0; j < 2; ++j) {
            int row = j * 64 + lane;
            size_t aoff = (size_t)(bm + row) * K + k0 + wave * 8;
            size_t boff = (size_t)(bn + row) * K + k0 + wave * 8;
            int s = (wave * 128 + j * 64) * 8;  // u16 index of wave-uniform base
            GLDS16(Ah + aoff, &lds[s]);
            GLDS16(Al + aoff, &lds[4096 + s]);
            GLDS16(Bh + boff, &lds[8192 + s]);
            GLDS16(Bl + boff, &lds[12288 + s]);
        }
        __syncthreads();  // drains vmcnt (full waitcnt before s_barrier)

        v8s ah[4], al[4], bh[4], bl[4];
#pragma unroll
        for (int i = 0; i < 4; ++i) {
            int ra = (quad * 128 + wm + i * 16 + r16) * 8;
            int rb = (quad * 128 + wn + i * 16 + r16) * 8;
            ah[i] = *(const v8s*)&lds[ra];
            al[i] = *(const v8s*)&lds[4096 + ra];
            bh[i] = *(const v8s*)&lds[8192 + rb];
            bl[i] = *(const v8s*)&lds[12288 + rb];
        }
#pragma unroll
        for (int i = 0; i < 4; ++i)
#pragma unroll
            for (int j = 0; j < 4; ++j) {
                acc[i][j] = __builtin_amdgcn_mfma_f32_16x16x32_bf16(ah[i], bh[j], acc[i][j], 0, 0, 0);
                acc[i][j] = __builtin_amdgcn_mfma_f32_16x16x32_bf16(ah[i], bl[j], acc[i][j], 0, 0, 0);
                acc[i][j] = __builtin_amdgcn_mfma_f32_16x16x32_bf16(al[i], bh[j], acc[i][j], 0, 0, 0);
            }
        __syncthreads();
    }

    // epilogue: C/D layout col=lane&15, row=quad*4+reg
#pragma unroll
    for (int i = 0; i < 4; ++i) {
        int gr0 = bm + wm + i * 16 + quad * 4;
#pragma unroll
        for (int j = 0; j < 4; ++j) {
            int gc = bn + wn + j * 16 + r16;
            float bv = BIAS ? bias[gc] : 0.f;
#pragma unroll
            for (int r = 0; r < 4; ++r) {
                int gr = gr0 + r;
                if (gr < M) C[(size_t)gr * N + gc] = acc[i][j][r] + bv;
            }
        }
    }
}

// =====================================================================
// CSR build
// =====================================================================
__global__ void count_k(const int* __restrict__ dst, int* __restrict__ cnt) {
    int e = blockIdx.x * blockDim.x + threadIdx.x;
    if (e < NE) atomicAdd(&cnt[dst[e]], 1);
}

__global__ void scan_k(const int* __restrict__ cnt, int* __restrict__ off,
                       int* __restrict__ cur) {
    __shared__ int ps[1024];
    const int tid = threadIdx.x;
    const int CH = (NN + 1023) / 1024;
    const int base = tid * CH;
    int s = 0;
    for (int i = 0; i < CH; ++i) {
        int idx = base + i;
        if (idx < NN) s += cnt[idx];
    }
    ps[tid] = s;
    __syncthreads();
    for (int d = 1; d < 1024; d <<= 1) {
        int v = (tid >= d) ? ps[tid - d] : 0;
        __syncthreads();
        ps[tid] += v;
        __syncthreads();
    }
    int run = (tid > 0) ? ps[tid - 1] : 0;
    for (int i = 0; i < CH; ++i) {
        int idx = base + i;
        if (idx <= NN) { off[idx] = run; if (idx < NN) cur[idx] = run; }
        if (idx < NN) run += cnt[idx];
    }
}

__global__ void fill_k(const int* __restrict__ src, const int* __restrict__ dst,
                       int* __restrict__ cur, int* __restrict__ elist) {
    int e = blockIdx.x * blockDim.x + threadIdx.x;
    if (e >= NE) return;
    int p = atomicAdd(&cur[dst[e]], 1);
    elist[p] = src[e];
}

// =====================================================================
// CSR gather: a[n,:] = sum_{e in in(n)} m[src(e),:]; emits bf16 hi/lo
// =====================================================================
template<int C>
__global__ void gather_k(const float* __restrict__ m, const int* __restrict__ off,
                         const int* __restrict__ elist,
                         u16* __restrict__ ah, u16* __restrict__ al) {
    constexpr int LPN = C / 4;
    int t = blockIdx.x * blockDim.x + threadIdx.x;
    int node = t / LPN;
    if (node >= NN) return;
    int c = (t % LPN) * 4;
    int s0 = off[node], s1 = off[node + 1];
    float4 acc = make_float4(0.f, 0.f, 0.f, 0.f);
    for (int i = s0; i < s1; ++i) {
        float4 v = *(const float4*)(m + (size_t)elist[i] * C + c);
        acc.x += v.x; acc.y += v.y; acc.z += v.z; acc.w += v.w;
    }
    ushort4 h, l;
    h.x = f2bf(acc.x); l.x = f2bf(acc.x - bf2f(h.x));
    h.y = f2bf(acc.y); l.y = f2bf(acc.y - bf2f(h.y));
    h.z = f2bf(acc.z); l.z = f2bf(acc.z - bf2f(h.z));
    h.w = f2bf(acc.w); l.w = f2bf(acc.w - bf2f(h.w));
    *(ushort4*)(ah + (size_t)node * C + c) = h;
    *(ushort4*)(al + (size_t)node * C + c) = l;
}

// =====================================================================
// GRU gates: x = (1-z)*n + z*h (in place), also emits bf16 hi/lo of x
// =====================================================================
template<int C>
__global__ void gates_k(const float* __restrict__ gi, const float* __restrict__ gh,
                        float* __restrict__ x, u16* __restrict__ xh,
                        u16* __restrict__ xl) {
    constexpr int Q = C / 4;
    int t = blockIdx.x * blockDim.x + threadIdx.x;
    if (t >= NN * Q) return;
    int n = t / Q, q = t - n * Q;
    const float4* gin = (const float4*)(gi + (size_t)n * 3 * C);
    const float4* ghn = (const float4*)(gh + (size_t)n * 3 * C);
    float4 ir = gin[q], iz = gin[Q + q], in_ = gin[2 * Q + q];
    float4 hr = ghn[q], hz = ghn[Q + q], hn = ghn[2 * Q + q];
    float4* xp = (float4*)(x + (size_t)n * C);
    float4 h = xp[q];
    float4 o;
#define GRU1(f)                                                       \
    {                                                                 \
        float r = 1.f / (1.f + expf(-(ir.f + hr.f)));                 \
        float z = 1.f / (1.f + expf(-(iz.f + hz.f)));                 \
        float nn_ = tanhf(in_.f + r * hn.f);                          \
        o.f = (1.f - z) * nn_ + z * h.f;                              \
    }
    GRU1(x) GRU1(y) GRU1(z) GRU1(w)
#undef GRU1
    xp[q] = o;
    ushort4 hh, ll;
    hh.x = f2bf(o.x); ll.x = f2bf(o.x - bf2f(hh.x));
    hh.y = f2bf(o.y); ll.y = f2bf(o.y - bf2f(hh.y));
    hh.z = f2bf(o.z); ll.z = f2bf(o.z - bf2f(hh.z));
    hh.w = f2bf(o.w); ll.w = f2bf(o.w - bf2f(hh.w));
    *(ushort4*)(xh + (size_t)n * C + q * 4) = hh;
    *(ushort4*)(xl + (size_t)n * C + q * 4) = ll;
}

// ------------- initial x: fp32 copy + bf16 hi/lo split -------------
__global__ void xinit_k(const float* __restrict__ xin, float* __restrict__ x,
                        u16* __restrict__ xh, u16* __restrict__ xl) {
    int t = blockIdx.x * blockDim.x + threadIdx.x;
    if (t >= NN * D1) return;
    float v = xin[t];
    x[t] = v;
    u16 h = f2bf(v);
    xh[t] = h;
    xl[t] = f2bf(v - bf2f(h));
}

// ------------- relu + pad 128->256, fp32 + bf16 hi/lo -------------
__global__ void relu_pad_k(const float* __restrict__ x1, float* __restrict__ x2,
                           u16* __restrict__ xh, u16* __restrict__ xl) {
    int t = blockIdx.x * blockDim.x + threadIdx.x;
    if (t >= NN * D2) return;
    int n = t >> 8, c = t & 255;
    float v = 0.f;
    if (c < D1) v = fmaxf(x1[n * D1 + c], 0.f);
    x2[t] = v;
    u16 h = f2bf(v);
    xh[t] = h;
    xl[t] = f2bf(v - bf2f(h));
}

// ------------- weight split (straight [N,K] layout) -------------
__global__ void wsplit_k(const float* __restrict__ w, u16* __restrict__ oh,
                         u16* __restrict__ ol, int total) {
    int t = blockIdx.x * blockDim.x + threadIdx.x;
    if (t >= total) return;
    float v = w[t];
    u16 h = f2bf(v);
    oh[t] = h;
    ol[t] = f2bf(v - bf2f(h));
}

// ------------- weight split + transpose: [L][K][N] -> [L][N][K] -------------
__global__ void wsplit_tr_k(const float* __restrict__ w, u16* __restrict__ oh,
                            u16* __restrict__ ol, int K, int N, int total) {
    int t = blockIdx.x * blockDim.x + threadIdx.x;
    if (t >= total) return;
    int l = t / (K * N);
    int rem = t - l * (K * N);
    int k = rem / N, n = rem - k * N;
    float v = w[t];
    u16 h = f2bf(v);
    int o = l * K * N + n * K + k;
    oh[o] = h;
    ol[o] = f2bf(v - bf2f(h));
}

// ------------- segment max pool (monotone uint mapping) -------------
__global__ void pool_init_k(unsigned* __restrict__ pool) {
    int t = blockIdx.x * blockDim.x + threadIdx.x;
    if (t < NG * D2) pool[t] = 0x007FFFFFu;  // mapped(-inf)
}

__global__ void pool_max_k(const float* __restrict__ x, const int* __restrict__ batch,
                           unsigned* __restrict__ pool, int total) {
    int t = blockIdx.x * blockDim.x + threadIdx.x;
    if (t >= total) return;
    int n = t >> 8, c = t & 255;
    unsigned b = __float_as_uint(x[t]);
    unsigned u = (b & 0x80000000u) ? ~b : (b | 0x80000000u);
    atomicMax(&pool[batch[n] * D2 + c], u);
}

__global__ void fc_k(const unsigned* __restrict__ pool, const float* __restrict__ w,
                     const float* __restrict__ b, float* __restrict__ out) {
    int t = blockIdx.x * blockDim.x + threadIdx.x;
    if (t >= NG * 6) return;
    int g = t / 6, o = t - g * 6;
    float s = b[o];
    for (int c = 0; c < D2; ++c) {
        unsigned u = pool[g * D2 + c];
        unsigned bits = (u & 0x80000000u) ? (u ^ 0x80000000u) : ~u;
        s += __uint_as_float(bits) * w[o * D2 + c];
    }
    out[t] = s;
}

// =======================================================================
extern "C" void kernel_launch(void* const* d_in, const int* in_sizes, int n_in,
                              void* d_out, int out_size, void* d_ws, size_t ws_size,
                              hipStream_t stream) {
    const float* x_in = (const float*)d_in[0];
    const int* ei = (const int*)d_in[1];
    const int* src = ei;
    const int* dst = ei + NE;
    const int* batch = (const int*)d_in[2];
    const float* w1   = (const float*)d_in[3];
    const float* wih1 = (const float*)d_in[4];
    const float* whh1 = (const float*)d_in[5];
    const float* bih1 = (const float*)d_in[6];
    const float* bhh1 = (const float*)d_in[7];
    const float* w2   = (const float*)d_in[8];
    const float* wih2 = (const float*)d_in[9];
    const float* whh2 = (const float*)d_in[10];
    const float* bih2 = (const float*)d_in[11];
    const float* bhh2 = (const float*)d_in[12];
    const float* fcw  = (const float*)d_in[13];
    const float* fcb  = (const float*)d_in[14];
    float* out = (float*)d_out;

    // ---- workspace layout (~91.5 MB) ----
    // aliasing: m and a_hi/a_lo live inside the gh buffer. Timeline per iter:
    //   mGEMM(writes m) -> gather(reads m, writes a_hl) -> giGEMM(reads a_hl)
    //   -> ghGEMM(overwrites whole gh region; m and a_hl already dead).
    // gi/gh GEMMs MUST be sequential launches (dual-z launch would race).
    float* ws = (float*)d_ws;
    float* gibuf = ws;                        // [NN, 768] fp32
    float* ghbuf = gibuf + NN * 768;          // [NN, 768] fp32
    float* mbuf  = ghbuf;                     // alias: [NN, <=256] fp32
    u16* a_h = (u16*)(ghbuf + NN * 256);      // [NN, 256] bf16
    u16* a_l = a_h + NN * 256;                // [NN, 256] bf16
    float* x1 = ghbuf + NN * 768;             // [NN, 128] fp32
    float* x2 = x1 + NN * 128;                // [NN, 256] fp32
    u16* x_h = (u16*)(x2 + NN * 256);         // [NN, 256] bf16 (layer1: stride 128)
    u16* x_l = x_h + NN * 256;
    u16* w1t_h = x_l + NN * 256;              // 3*128*128 (transposed [N,K])
    u16* w1t_l  = w1t_h + 3 * D1 * D1;
    u16* w2t_h  = w1t_l + 3 * D1 * D1;        // 3*256*256
    u16* w2t_l  = w2t_h + 3 * D2 * D2;
    u16* wih1_h = w2t_l + 3 * D2 * D2;        // 384*128 = 3*D1*D1
    u16* wih1_l = wih1_h + 3 * D1 * D1;
    u16* whh1_h = wih1_l + 3 * D1 * D1;
    u16* whh1_l = whh1_h + 3 * D1 * D1;
    u16* wih2_h = whh1_l + 3 * D1 * D1;       // 768*256 = 3*D2*D2
    u16* wih2_l = wih2_h + 3 * D2 * D2;
    u16* whh2_h = wih2_l + 3 * D2 * D2;
    u16* whh2_l = whh2_h + 3 * D2 * D2;
    int* cnt   = (int*)(whh2_l + 3 * D2 * D2);
    int* off   = cnt + NN;
    int* cur   = off + NN + 1;
    int* elist = cur + NN;
    unsigned* pool = (unsigned*)(elist + NE);

    // ---- CSR build ----
    hipMemsetAsync(cnt, 0, NN * sizeof(int), stream);
    count_k<<<(NE + 255) / 256, 256, 0, stream>>>(dst, cnt);
    scan_k<<<1, 1024, 0, stream>>>(cnt, off, cur);
    fill_k<<<(NE + 255) / 256, 256, 0, stream>>>(src, dst, cur, elist);

    // ---- weight conversion (per call: graph replay re-poisons ws) ----
    wsplit_tr_k<<<(3 * D1 * D1 + 255) / 256, 256, 0, stream>>>(w1, w1t_h, w1t_l, D1, D1, 3 * D1 * D1);
    wsplit_tr_k<<<(3 * D2 * D2 + 255) / 256, 256, 0, stream>>>(w2, w2t_h, w2t_l, D2, D2, 3 * D2 * D2);
    wsplit_k<<<(3 * D1 * D1 + 255) / 256, 256, 0, stream>>>(wih1, wih1_h, wih1_l, 3 * D1 * D1);
    wsplit_k<<<(3 * D1 * D1 + 255) / 256, 256, 0, stream>>>(whh1, whh1_h, whh1_l, 3 * D1 * D1);
    wsplit_k<<<(3 * D2 * D2 + 255) / 256, 256, 0, stream>>>(wih2, wih2_h, wih2_l, 3 * D2 * D2);
    wsplit_k<<<(3 * D2 * D2 + 255) / 256, 256, 0, stream>>>(whh2, whh2_h, whh2_l, 3 * D2 * D2);

    xinit_k<<<(NN * D1 + 255) / 256, 256, 0, stream>>>(x_in, x1, x_h, x_l);

    const int MT = (NN + 127) / 128;  // 79

    // ---------------- layer 1 (C = 128) ----------------
    for (int it = 0; it < 3; ++it) {
        const int C = D1;
        mgemm_k<false><<<dim3(C / 128, MT, 1), 256, 0, stream>>>(
            x_h, x_l, w1t_h + it * C * C, w1t_l + it * C * C, nullptr, mbuf, NN, C, C);
        gather_k<D1><<<(NN * (D1 / 4) + 255) / 256, 256, 0, stream>>>(mbuf, off, elist, a_h, a_l);
        mgemm_k<true><<<dim3(3 * C / 128, MT, 1), 256, 0, stream>>>(
            a_h, a_l, wih1_h, wih1_l, bih1, gibuf, NN, 3 * C, C);
        mgemm_k<true><<<dim3(3 * C / 128, MT, 1), 256, 0, stream>>>(
            x_h, x_l, whh1_h, whh1_l, bhh1, ghbuf, NN, 3 * C, C);
        gates_k<D1><<<(NN * (D1 / 4) + 255) / 256, 256, 0, stream>>>(gibuf, ghbuf, x1, x_h, x_l);
    }

    relu_pad_k<<<(NN * D2 + 255) / 256, 256, 0, stream>>>(x1, x2, x_h, x_l);

    // ---------------- layer 2 (C = 256) ----------------
    for (int it = 0; it < 3; ++it) {
        const int C = D2;
        mgemm_k<false><<<dim3(C / 128, MT, 1), 256, 0, stream>>>(
            x_h, x_l, w2t_h + it * C * C, w2t_l + it * C * C, nullptr, mbuf, NN, C, C);
        gather_k<D2><<<(NN * (D2 / 4) + 255) / 256, 256, 0, stream>>>(mbuf, off, elist, a_h, a_l);
        mgemm_k<true><<<dim3(3 * C / 128, MT, 1), 256, 0, stream>>>(
            a_h, a_l, wih2_h, wih2_l, bih2, gibuf, NN, 3 * C, C);
        mgemm_k<true><<<dim3(3 * C / 128, MT, 1), 256, 0, stream>>>(
            x_h, x_l, whh2_h, whh2_l, bhh2, ghbuf, NN, 3 * C, C);
        gates_k<D2><<<(NN * (D2 / 4) + 255) / 256, 256, 0, stream>>>(gibuf, ghbuf, x2, x_h, x_l);
    }

    // ---------------- global max pool + FC ----------------
    pool_init_k<<<(NG * D2 + 255) / 256, 256, 0, stream>>>(pool);
    pool_max_k<<<(NN * D2 + 255) / 256, 256, 0, stream>>>(x2, batch, pool, NN * D2);
    fc_k<<<1, 512, 0, stream>>>(pool, fcw, fcb, out);
}

// Round 4
// 722.896 us; speedup vs baseline: 7.8901x; 1.1483x over previous
//
#include <hip/hip_runtime.h>

#define NN 10000
#define NE 320000
#define NG 64
#define D1 128
#define D2 256

typedef unsigned short u16;
typedef short v8s __attribute__((ext_vector_type(8)));
typedef float v4f __attribute__((ext_vector_type(4)));

__device__ __forceinline__ u16 f2bf(float x) {
    unsigned u = __float_as_uint(x);
    return (u16)((u + 0x7fffu + ((u >> 16) & 1u)) >> 16);
}
__device__ __forceinline__ float bf2f(u16 b) {
    return __uint_as_float(((unsigned)b) << 16);
}

// async global->LDS, 16B per lane; LDS dest = wave-uniform base + lane*16
#define GLDS16(gp, lp)                                                         \
    __builtin_amdgcn_global_load_lds(                                          \
        (__attribute__((address_space(1))) unsigned int*)(unsigned long long)(gp), \
        (__attribute__((address_space(3))) unsigned int*)(lp), 16, 0, 0)

// =====================================================================
// Split-bf16 MFMA GEMM: D[M,N] = (Ah+Al)[M,K] @ (Bh+Bl)[N,K]^T
// 128x128 block tile, 4 waves, 64x64/wave, 16x16x32 mfma, BK=32,
// 3 mfma per frag pair (drop lo*lo).
// SPLIT: columns < N0 -> Cm (no bias, row stride N0);
//        columns >= N0 -> Cg (+bias[gc-N0], row stride N-N0).
// N0 is a multiple of 128 so the branch is block-uniform.
// !SPLIT: everything -> Cg (+bias), row stride N.
// A rows >= M read slack ws memory (those D rows are never stored).
// =====================================================================
template<bool SPLIT>
__global__ __launch_bounds__(256)
void mgemm_k(const u16* __restrict__ Ah, const u16* __restrict__ Al,
             const u16* __restrict__ Bh, const u16* __restrict__ Bl,
             const float* __restrict__ bias, float* __restrict__ Cm,
             float* __restrict__ Cg, int M, int N, int K, int N0) {
    __shared__ u16 lds[16384];
    const int tid = threadIdx.x;
    const int wave = tid >> 6, lane = tid & 63;
    const int wm = (wave >> 1) * 64, wn = (wave & 1) * 64;
    const int bm = blockIdx.y * 128, bn = blockIdx.x * 128;
    const int quad = lane >> 4, r16 = lane & 15;

    v4f acc[4][4] = {};

    for (int k0 = 0; k0 < K; k0 += 32) {
#pragma unroll
        for (int j = 0; j < 2; ++j) {
            int row = j * 64 + lane;
            size_t aoff = (size_t)(bm + row) * K + k0 + wave * 8;
            size_t boff = (size_t)(bn + row) * K + k0 + wave * 8;
            int s = (wave * 128 + j * 64) * 8;
            GLDS16(Ah + aoff, &lds[s]);
            GLDS16(Al + aoff, &lds[4096 + s]);
            GLDS16(Bh + boff, &lds[8192 + s]);
            GLDS16(Bl + boff, &lds[12288 + s]);
        }
        __syncthreads();

        v8s ah[4], al[4], bh[4], bl[4];
#pragma unroll
        for (int i = 0; i < 4; ++i) {
            int ra = (quad * 128 + wm + i * 16 + r16) * 8;
            int rb = (quad * 128 + wn + i * 16 + r16) * 8;
            ah[i] = *(const v8s*)&lds[ra];
            al[i] = *(const v8s*)&lds[4096 + ra];
            bh[i] = *(const v8s*)&lds[8192 + rb];
            bl[i] = *(const v8s*)&lds[12288 + rb];
        }
#pragma unroll
        for (int i = 0; i < 4; ++i)
#pragma unroll
            for (int j = 0; j < 4; ++j) {
                acc[i][j] = __builtin_amdgcn_mfma_f32_16x16x32_bf16(ah[i], bh[j], acc[i][j], 0, 0, 0);
                acc[i][j] = __builtin_amdgcn_mfma_f32_16x16x32_bf16(ah[i], bl[j], acc[i][j], 0, 0, 0);
                acc[i][j] = __builtin_amdgcn_mfma_f32_16x16x32_bf16(al[i], bh[j], acc[i][j], 0, 0, 0);
            }
        __syncthreads();
    }

    // epilogue: C/D layout col=lane&15, row=quad*4+reg
#pragma unroll
    for (int i = 0; i < 4; ++i) {
        int gr0 = bm + wm + i * 16 + quad * 4;
#pragma unroll
        for (int j = 0; j < 4; ++j) {
            int gc = bn + wn + j * 16 + r16;
            if (SPLIT && gc < N0) {  // block-uniform branch
#pragma unroll
                for (int r = 0; r < 4; ++r) {
                    int gr = gr0 + r;
                    if (gr < M) Cm[(size_t)gr * N0 + gc] = acc[i][j][r];
                }
            } else {
                int cc = SPLIT ? gc - N0 : gc;
                int ns = SPLIT ? N - N0 : N;
                float bv = bias[cc];
#pragma unroll
                for (int r = 0; r < 4; ++r) {
                    int gr = gr0 + r;
                    if (gr < M) Cg[(size_t)gr * ns + cc] = acc[i][j][r] + bv;
                }
            }
        }
    }
}

// =====================================================================
// CSR build
// =====================================================================
__global__ void count_k(const int* __restrict__ dst, int* __restrict__ cnt) {
    int e = blockIdx.x * blockDim.x + threadIdx.x;
    if (e < NE) atomicAdd(&cnt[dst[e]], 1);
}

__global__ void scan_k(const int* __restrict__ cnt, int* __restrict__ off,
                       int* __restrict__ cur) {
    __shared__ int ps[1024];
    const int tid = threadIdx.x;
    const int CH = (NN + 1023) / 1024;
    const int base = tid * CH;
    int s = 0;
    for (int i = 0; i < CH; ++i) {
        int idx = base + i;
        if (idx < NN) s += cnt[idx];
    }
    ps[tid] = s;
    __syncthreads();
    for (int d = 1; d < 1024; d <<= 1) {
        int v = (tid >= d) ? ps[tid - d] : 0;
        __syncthreads();
        ps[tid] += v;
        __syncthreads();
    }
    int run = (tid > 0) ? ps[tid - 1] : 0;
    for (int i = 0; i < CH; ++i) {
        int idx = base + i;
        if (idx <= NN) { off[idx] = run; if (idx < NN) cur[idx] = run; }
        if (idx < NN) run += cnt[idx];
    }
}

__global__ void fill_k(const int* __restrict__ src, const int* __restrict__ dst,
                       int* __restrict__ cur, int* __restrict__ elist) {
    int e = blockIdx.x * blockDim.x + threadIdx.x;
    if (e >= NE) return;
    int p = atomicAdd(&cur[dst[e]], 1);
    elist[p] = src[e];
}

// =====================================================================
// CSR gather, 4-deep software pipeline: a[n,:] = sum m[src,:], bf16 hi/lo out
// =====================================================================
template<int C>
__global__ void gather_k(const float* __restrict__ m, const int* __restrict__ off,
                         const int* __restrict__ elist,
                         u16* __restrict__ ah, u16* __restrict__ al) {
    constexpr int LPN = C / 4;
    int t = blockIdx.x * blockDim.x + threadIdx.x;
    int node = t / LPN;
    if (node >= NN) return;
    int c = (t % LPN) * 4;
    int s0 = off[node], s1 = off[node + 1];
    v4f a0 = 0.f, a1 = 0.f, a2 = 0.f, a3 = 0.f;
    int i = s0;
    for (; i + 4 <= s1; i += 4) {
        int e0 = elist[i], e1 = elist[i + 1], e2 = elist[i + 2], e3 = elist[i + 3];
        v4f v0 = *(const v4f*)(m + (size_t)e0 * C + c);
        v4f v1 = *(const v4f*)(m + (size_t)e1 * C + c);
        v4f v2 = *(const v4f*)(m + (size_t)e2 * C + c);
        v4f v3 = *(const v4f*)(m + (size_t)e3 * C + c);
        a0 += v0; a1 += v1; a2 += v2; a3 += v3;
    }
    for (; i < s1; ++i) {
        int e = elist[i];
        a0 += *(const v4f*)(m + (size_t)e * C + c);
    }
    v4f acc = (a0 + a1) + (a2 + a3);
    ushort4 h, l;
    h.x = f2bf(acc.x); l.x = f2bf(acc.x - bf2f(h.x));
    h.y = f2bf(acc.y); l.y = f2bf(acc.y - bf2f(h.y));
    h.z = f2bf(acc.z); l.z = f2bf(acc.z - bf2f(h.z));
    h.w = f2bf(acc.w); l.w = f2bf(acc.w - bf2f(h.w));
    *(ushort4*)(ah + (size_t)node * C + c) = h;
    *(ushort4*)(al + (size_t)node * C + c) = l;
}

// =====================================================================
// GRU gates: x = (1-z)*n + z*h (in place), emits bf16 hi/lo of x
// =====================================================================
template<int C>
__global__ void gates_k(const float* __restrict__ gi, const float* __restrict__ gh,
                        float* __restrict__ x, u16* __restrict__ xh,
                        u16* __restrict__ xl) {
    constexpr int Q = C / 4;
    int t = blockIdx.x * blockDim.x + threadIdx.x;
    if (t >= NN * Q) return;
    int n = t / Q, q = t - n * Q;
    const float4* gin = (const float4*)(gi + (size_t)n * 3 * C);
    const float4* ghn = (const float4*)(gh + (size_t)n * 3 * C);
    float4 ir = gin[q], iz = gin[Q + q], in_ = gin[2 * Q + q];
    float4 hr = ghn[q], hz = ghn[Q + q], hn = ghn[2 * Q + q];
    float4* xp = (float4*)(x + (size_t)n * C);
    float4 h = xp[q];
    float4 o;
#define GRU1(f)                                                       \
    {                                                                 \
        float r = 1.f / (1.f + expf(-(ir.f + hr.f)));                 \
        float z = 1.f / (1.f + expf(-(iz.f + hz.f)));                 \
        float nn_ = tanhf(in_.f + r * hn.f);                          \
        o.f = (1.f - z) * nn_ + z * h.f;                              \
    }
    GRU1(x) GRU1(y) GRU1(z) GRU1(w)
#undef GRU1
    xp[q] = o;
    ushort4 hh, ll;
    hh.x = f2bf(o.x); ll.x = f2bf(o.x - bf2f(hh.x));
    hh.y = f2bf(o.y); ll.y = f2bf(o.y - bf2f(hh.y));
    hh.z = f2bf(o.z); ll.z = f2bf(o.z - bf2f(hh.z));
    hh.w = f2bf(o.w); ll.w = f2bf(o.w - bf2f(hh.w));
    *(ushort4*)(xh + (size_t)n * C + q * 4) = hh;
    *(ushort4*)(xl + (size_t)n * C + q * 4) = ll;
}

// ------------- initial x: fp32 copy + bf16 hi/lo split -------------
__global__ void xinit_k(const float* __restrict__ xin, float* __restrict__ x,
                        u16* __restrict__ xh, u16* __restrict__ xl) {
    int t = blockIdx.x * blockDim.x + threadIdx.x;
    if (t >= NN * D1) return;
    float v = xin[t];
    x[t] = v;
    u16 h = f2bf(v);
    xh[t] = h;
    xl[t] = f2bf(v - bf2f(h));
}

// ------------- relu + pad 128->256, fp32 + bf16 hi/lo -------------
__global__ void relu_pad_k(const float* __restrict__ x1, float* __restrict__ x2,
                           u16* __restrict__ xh, u16* __restrict__ xl) {
    int t = blockIdx.x * blockDim.x + threadIdx.x;
    if (t >= NN * D2) return;
    int n = t >> 8, c = t & 255;
    float v = 0.f;
    if (c < D1) v = fmaxf(x1[n * D1 + c], 0.f);
    x2[t] = v;
    u16 h = f2bf(v);
    xh[t] = h;
    xl[t] = f2bf(v - bf2f(h));
}

// =====================================================================
// prep_k: all weight conversions in one launch.
// B1cat[it] = [512,128]:  rows 0..127  = w1[it]^T, rows 128..511 = whh1
// B2cat[it] = [1024,256]: rows 0..255  = w2[it]^T, rows 256..1023 = whh2
// wih1/wih2 split straight ([3C,C] row-major, already B layout).
// =====================================================================
__global__ void prep_k(const float* __restrict__ w1, const float* __restrict__ whh1,
                       const float* __restrict__ wih1, const float* __restrict__ w2,
                       const float* __restrict__ whh2, const float* __restrict__ wih2,
                       u16* __restrict__ B1h, u16* __restrict__ B1l,
                       u16* __restrict__ B2h, u16* __restrict__ B2l,
                       u16* __restrict__ wih1h, u16* __restrict__ wih1l,
                       u16* __restrict__ wih2h, u16* __restrict__ wih2l) {
    const int n1 = 3 * D1 * D1, n2 = 3 * D2 * D2;
    int t = blockIdx.x * blockDim.x + threadIdx.x;
    if (t < n1) {  // w1 transpose
        int l = t / (D1 * D1), rem = t - l * D1 * D1;
        int k = rem / D1, n = rem - k * D1;
        float v = w1[t]; u16 h = f2bf(v), lo = f2bf(v - bf2f(h));
        int o = (l * 512 + n) * D1 + k;
        B1h[o] = h; B1l[o] = lo; return;
    }
    t -= n1;
    if (t < n1) {  // whh1 replicate x3
        float v = whh1[t]; u16 h = f2bf(v), lo = f2bf(v - bf2f(h));
        int r = t / D1, k = t - r * D1;
#pragma unroll
        for (int l = 0; l < 3; ++l) {
            int o = (l * 512 + 128 + r) * D1 + k;
            B1h[o] = h; B1l[o] = lo;
        }
        return;
    }
    t -= n1;
    if (t < n2) {  // w2 transpose
        int l = t / (D2 * D2), rem = t - l * D2 * D2;
        int k = rem / D2, n = rem - k * D2;
        float v = w2[t]; u16 h = f2bf(v), lo = f2bf(v - bf2f(h));
        int o = (l * 1024 + n) * D2 + k;
        B2h[o] = h; B2l[o] = lo; return;
    }
    t -= n2;
    if (t < n2) {  // whh2 replicate x3
        float v = whh2[t]; u16 h = f2bf(v), lo = f2bf(v - bf2f(h));
        int r = t / D2, k = t - r * D2;
#pragma unroll
        for (int l = 0; l < 3; ++l) {
            int o = (l * 1024 + 256 + r) * D2 + k;
            B2h[o] = h; B2l[o] = lo;
        }
        return;
    }
    t -= n2;
    if (t < n1) { float v = wih1[t]; u16 h = f2bf(v); wih1h[t] = h; wih1l[t] = f2bf(v - bf2f(h)); return; }
    t -= n1;
    if (t < n2) { float v = wih2[t]; u16 h = f2bf(v); wih2h[t] = h; wih2l[t] = f2bf(v - bf2f(h)); }
}

// ------------- segment max pool (monotone uint mapping) -------------
__global__ void pool_init_k(unsigned* __restrict__ pool) {
    int t = blockIdx.x * blockDim.x + threadIdx.x;
    if (t < NG * D2) pool[t] = 0x007FFFFFu;  // mapped(-inf)
}

__global__ void pool_max_k(const float* __restrict__ x, const int* __restrict__ batch,
                           unsigned* __restrict__ pool, int total) {
    int t = blockIdx.x * blockDim.x + threadIdx.x;
    if (t >= total) return;
    int n = t >> 8, c = t & 255;
    unsigned b = __float_as_uint(x[t]);
    unsigned u = (b & 0x80000000u) ? ~b : (b | 0x80000000u);
    atomicMax(&pool[batch[n] * D2 + c], u);
}

__global__ void fc_k(const unsigned* __restrict__ pool, const float* __restrict__ w,
                     const float* __restrict__ b, float* __restrict__ out) {
    int t = blockIdx.x * blockDim.x + threadIdx.x;
    if (t >= NG * 6) return;
    int g = t / 6, o = t - g * 6;
    float s = b[o];
    for (int c = 0; c < D2; ++c) {
        unsigned u = pool[g * D2 + c];
        unsigned bits = (u & 0x80000000u) ? (u ^ 0x80000000u) : ~u;
        s += __uint_as_float(bits) * w[o * D2 + c];
    }
    out[t] = s;
}

// =======================================================================
extern "C" void kernel_launch(void* const* d_in, const int* in_sizes, int n_in,
                              void* d_out, int out_size, void* d_ws, size_t ws_size,
                              hipStream_t stream) {
    const float* x_in = (const float*)d_in[0];
    const int* ei = (const int*)d_in[1];
    const int* src = ei;
    const int* dst = ei + NE;
    const int* batch = (const int*)d_in[2];
    const float* w1   = (const float*)d_in[3];
    const float* wih1 = (const float*)d_in[4];
    const float* whh1 = (const float*)d_in[5];
    const float* bih1 = (const float*)d_in[6];
    const float* bhh1 = (const float*)d_in[7];
    const float* w2   = (const float*)d_in[8];
    const float* wih2 = (const float*)d_in[9];
    const float* whh2 = (const float*)d_in[10];
    const float* bih2 = (const float*)d_in[11];
    const float* bhh2 = (const float*)d_in[12];
    const float* fcw  = (const float*)d_in[13];
    const float* fcb  = (const float*)d_in[14];
    float* out = (float*)d_out;

    // ---- workspace layout (~104 MB) ----
    // mbuf aliases gibuf: per iter, fused GEMM writes m -> gather reads m,
    // writes a_hl -> gi GEMM overwrites gibuf (m dead). gh separate buffer.
    float* ws = (float*)d_ws;
    float* gibuf = ws;                        // [NN,768] fp32
    float* mbuf  = gibuf;                     // alias [NN,<=256] fp32
    float* ghbuf = gibuf + NN * 768;          // [NN,768] fp32
    u16* a_h = (u16*)(ghbuf + NN * 768);      // [NN,256] bf16
    u16* a_l = a_h + NN * 256;
    float* x1 = (float*)(a_l + NN * 256);     // [NN,128] fp32
    float* x2 = x1 + NN * 128;                // [NN,256] fp32
    u16* x_h = (u16*)(x2 + NN * 256);         // [NN,256] bf16 (layer1 stride 128)
    u16* x_l = x_h + NN * 256;
    u16* B1h = x_l + NN * 256;                // [3][512][128]
    u16* B1l = B1h + 3 * 512 * D1;
    u16* B2h = B1l + 3 * 512 * D1;            // [3][1024][256]
    u16* B2l = B2h + 3 * 1024 * D2;
    u16* wih1h = B2l + 3 * 1024 * D2;         // [384,128]
    u16* wih1l = wih1h + 3 * D1 * D1;
    u16* wih2h = wih1l + 3 * D1 * D1;         // [768,256]
    u16* wih2l = wih2h + 3 * D2 * D2;
    int* cnt   = (int*)(wih2l + 3 * D2 * D2);
    int* off   = cnt + NN;
    int* cur   = off + NN + 1;
    int* elist = cur + NN;
    unsigned* pool = (unsigned*)(elist + NE);

    // ---- CSR build ----
    hipMemsetAsync(cnt, 0, NN * sizeof(int), stream);
    count_k<<<(NE + 255) / 256, 256, 0, stream>>>(dst, cnt);
    scan_k<<<1, 1024, 0, stream>>>(cnt, off, cur);
    fill_k<<<(NE + 255) / 256, 256, 0, stream>>>(src, dst, cur, elist);

    // ---- weight conversion (single launch) ----
    {
        int total = 3 * (3 * D1 * D1) + 3 * (3 * D2 * D2);
        prep_k<<<(total + 255) / 256, 256, 0, stream>>>(
            w1, whh1, wih1, w2, whh2, wih2,
            B1h, B1l, B2h, B2l, wih1h, wih1l, wih2h, wih2l);
    }

    xinit_k<<<(NN * D1 + 255) / 256, 256, 0, stream>>>(x_in, x1, x_h, x_l);

    const int MT = (NN + 127) / 128;  // 79

    // ---------------- layer 1 (C = 128) ----------------
    for (int it = 0; it < 3; ++it) {
        const int C = D1;
        // fused: m = x@w[it] (cols 0..C-1), gh = x@whh^T + bhh (cols C..4C-1)
        mgemm_k<true><<<dim3(4 * C / 128, MT), 256, 0, stream>>>(
            x_h, x_l, B1h + it * 512 * C, B1l + it * 512 * C,
            bhh1, mbuf, ghbuf, NN, 4 * C, C, C);
        gather_k<D1><<<(NN * (D1 / 4) + 255) / 256, 256, 0, stream>>>(
            mbuf, off, elist, a_h, a_l);
        mgemm_k<false><<<dim3(3 * C / 128, MT), 256, 0, stream>>>(
            a_h, a_l, wih1h, wih1l, bih1, nullptr, gibuf, NN, 3 * C, C, 0);
        gates_k<D1><<<(NN * (D1 / 4) + 255) / 256, 256, 0, stream>>>(
            gibuf, ghbuf, x1, x_h, x_l);
    }

    relu_pad_k<<<(NN * D2 + 255) / 256, 256, 0, stream>>>(x1, x2, x_h, x_l);

    // ---------------- layer 2 (C = 256) ----------------
    for (int it = 0; it < 3; ++it) {
        const int C = D2;
        mgemm_k<true><<<dim3(4 * C / 128, MT), 256, 0, stream>>>(
            x_h, x_l, B2h + it * 1024 * C, B2l + it * 1024 * C,
            bhh2, mbuf, ghbuf, NN, 4 * C, C, C);
        gather_k<D2><<<(NN * (D2 / 4) + 255) / 256, 256, 0, stream>>>(
            mbuf, off, elist, a_h, a_l);
        mgemm_k<false><<<dim3(3 * C / 128, MT), 256, 0, stream>>>(
            a_h, a_l, wih2h, wih2l, bih2, nullptr, gibuf, NN, 3 * C, C, 0);
        gates_k<D2><<<(NN * (D2 / 4) + 255) / 256, 256, 0, stream>>>(
            gibuf, ghbuf, x2, x_h, x_l);
    }

    // ---------------- global max pool + FC ----------------
    pool_init_k<<<(NG * D2 + 255) / 256, 256, 0, stream>>>(pool);
    pool_max_k<<<(NN * D2 + 255) / 256, 256, 0, stream>>>(x2, batch, pool, NN * D2);
    fc_k<<<1, 512, 0, stream>>>(pool, fcw, fcb, out);
}